// Round 5
// baseline (148.646 us; speedup 1.0000x reference)
//
#include <hip/hip_runtime.h>

// CondMul: out[n] = input[n] @ w[inds[n]] + b[inds[n]]
// N=262144 rows, 1024 experts, in=out=32, fp32.
//
// v5: measured-best recombination.
//  - R4 showed the xs-permute scatter costs 45us (64-block parallelism +
//    67MB extra round-trip); gather-in-condmul never pays that -> dropped.
//  - Condmul: one block per class, w in LDS (broadcast ds_read_b128, low
//    VGPR), TWO row-streams per iteration so each LDS w read feeds 2 rows
//    (v1 paid ~20us of LDS-pipe issue at 1 stream; 2 streams halve it below
//    the ~14us memory time) while keeping ~90 VGPR -> 5 waves/SIMD
//    (v3's reg-w at 2 waves/SIMD was a +34us latency regression).
//  - Scatter writes row IDS only (4B), LDS cursors, deterministic.
//  - Scan caches per-block counts in registers (64 VGPR, static unroll).
// Fixed harness overhead: 2x ~44us 256MiB workspace-poison fills are
// included in dur_us; controllable kernel budget is ~28us.

#define N_ROWS      262144
#define N_CLASSES   1024
#define IN_F        32
#define OUT_F       32
#define HB          64
#define ROWS_PER_HB (N_ROWS / HB)   // 4096, exact

// ---------------- K1: per-block histogram (LDS atomics) ----------------
__global__ __launch_bounds__(1024) void k_hist(const int* __restrict__ inds,
                                               int* __restrict__ bc) {
    __shared__ int h[N_CLASSES];
    const int tid = threadIdx.x;
    h[tid] = 0;
    __syncthreads();
    const int base = blockIdx.x * ROWS_PER_HB;
    for (int k = 0; k < ROWS_PER_HB; k += 1024)
        atomicAdd(&h[inds[base + k + tid]], 1);
    __syncthreads();
    bc[blockIdx.x * N_CLASSES + tid] = h[tid];
}

// ------- K2: single block; totals (counts cached in regs), scan, offsets -------
// Thread c handles class c: loads bc[b][c] for all b (coalesced), keeps them
// in registers (HB=64 VGPRs, static indexing), scans class totals in LDS,
// writes per-(block,class) start offsets back with zero global re-reads.
__global__ __launch_bounds__(1024) void k_scan(int* __restrict__ bc,
                                               int* __restrict__ cls_off) {
    __shared__ int s[N_CLASSES];
    const int c = threadIdx.x;  // 1024 threads == N_CLASSES
    int v[HB];
    int total = 0;
#pragma unroll
    for (int b = 0; b < HB; ++b) {
        v[b] = bc[b * N_CLASSES + c];
        total += v[b];
    }
    s[c] = total;
    __syncthreads();
    // Hillis-Steele inclusive scan over classes
    for (int off = 1; off < N_CLASSES; off <<= 1) {
        int t = (c >= off) ? s[c - off] : 0;
        __syncthreads();
        s[c] += t;
        __syncthreads();
    }
    int run = s[c] - total;  // exclusive prefix = class base
    cls_off[c] = run;
    if (c == N_CLASSES - 1) cls_off[N_CLASSES] = s[c];  // == N_ROWS
#pragma unroll
    for (int b = 0; b < HB; ++b) {
        const int t = v[b];
        bc[b * N_CLASSES + c] = run;  // start offset for (hist-block b, class c)
        run += t;
    }
}

// ---------------- K3: scatter row ids into buckets (LDS cursors) ----------------
// Deterministic: block b's cursor for class c starts at the precomputed
// global offset; all atomics are LDS-local.
__global__ __launch_bounds__(1024) void k_scatter(const int* __restrict__ inds,
                                                  const int* __restrict__ bc,
                                                  int* __restrict__ rowids) {
    __shared__ int cur[N_CLASSES];
    const int tid = threadIdx.x;
    cur[tid] = bc[blockIdx.x * N_CLASSES + tid];
    __syncthreads();
    const int base = blockIdx.x * ROWS_PER_HB;
    for (int k = 0; k < ROWS_PER_HB; k += 1024) {
        const int row = base + k + tid;
        const int c = inds[row];
        const int pos = atomicAdd(&cur[c], 1);
        rowids[pos] = row;
    }
}

// ---------------- K4: one block per expert, w in LDS, 2 row-streams ----------------
// 256 threads = 4 waves. Lane -> (row slot rg = tid>>3, out-quad oq = tid&7).
// Per iteration the block does 64 rows in 2 streams (A: it*64+rg, B: +32);
// each LDS w read feeds both streams. Input rows gathered via rowids (random
// 128B reads, hidden by ~20 waves/CU); out write scattered 128B.
__global__ __launch_bounds__(256) void k_condmul(const float* __restrict__ input,
                                                 const float* __restrict__ w,
                                                 const float* __restrict__ bias,
                                                 const int* __restrict__ rowids,
                                                 const int* __restrict__ cls_off,
                                                 float* __restrict__ out) {
    __shared__ float wlds[IN_F * OUT_F];  // 4 KiB
    const int cls = blockIdx.x;
    const int tid = threadIdx.x;
    ((float4*)wlds)[tid] = ((const float4*)(w + (size_t)cls * IN_F * OUT_F))[tid];

    const int oq = tid & 7;   // output quad
    const int rg = tid >> 3;  // row slot 0..31
    const int start = cls_off[cls];
    const int count = cls_off[cls + 1] - start;
    const float4 bv = ((const float4*)(bias + (size_t)cls * OUT_F))[oq];
    __syncthreads();
    if (count <= 0) return;

    const float4* wl4 = (const float4*)wlds;
    const int iters = (count + 63) >> 6;
    for (int it = 0; it < iters; ++it) {
        const int riA = it * 64 + rg;
        const int riB = riA + 32;
        const bool va = riA < count;
        const bool vb = riB < count;
        const int rowA = rowids[start + (va ? riA : count - 1)];
        const int rowB = rowids[start + (vb ? riB : count - 1)];

        const float4* xa4 = (const float4*)(input + (size_t)rowA * IN_F);
        const float4* xb4 = (const float4*)(input + (size_t)rowB * IN_F);
        float4 xa[8], xb[8];
#pragma unroll
        for (int j = 0; j < 8; ++j) xa[j] = xa4[j];
#pragma unroll
        for (int j = 0; j < 8; ++j) xb[j] = xb4[j];

        float4 accA = bv;
        float4 accB = bv;
#pragma unroll
        for (int j = 0; j < 8; ++j) {
            const float a0 = xa[j].x, a1 = xa[j].y, a2 = xa[j].z, a3 = xa[j].w;
            const float b0 = xb[j].x, b1 = xb[j].y, b2 = xb[j].z, b3 = xb[j].w;
            const float4 w0 = wl4[(j * 4 + 0) * (OUT_F / 4) + oq];
            const float4 w1 = wl4[(j * 4 + 1) * (OUT_F / 4) + oq];
            const float4 w2 = wl4[(j * 4 + 2) * (OUT_F / 4) + oq];
            const float4 w3 = wl4[(j * 4 + 3) * (OUT_F / 4) + oq];
            accA.x += a0 * w0.x; accA.y += a0 * w0.y; accA.z += a0 * w0.z; accA.w += a0 * w0.w;
            accA.x += a1 * w1.x; accA.y += a1 * w1.y; accA.z += a1 * w1.z; accA.w += a1 * w1.w;
            accA.x += a2 * w2.x; accA.y += a2 * w2.y; accA.z += a2 * w2.z; accA.w += a2 * w2.w;
            accA.x += a3 * w3.x; accA.y += a3 * w3.y; accA.z += a3 * w3.z; accA.w += a3 * w3.w;
            accB.x += b0 * w0.x; accB.y += b0 * w0.y; accB.z += b0 * w0.z; accB.w += b0 * w0.w;
            accB.x += b1 * w1.x; accB.y += b1 * w1.y; accB.z += b1 * w1.z; accB.w += b1 * w1.w;
            accB.x += b2 * w2.x; accB.y += b2 * w2.y; accB.z += b2 * w2.z; accB.w += b2 * w2.w;
            accB.x += b3 * w3.x; accB.y += b3 * w3.y; accB.z += b3 * w3.z; accB.w += b3 * w3.w;
        }
        if (va) ((float4*)(out + (size_t)rowA * OUT_F))[oq] = accA;
        if (vb) ((float4*)(out + (size_t)rowB * OUT_F))[oq] = accB;
    }
}

// ---------------- fallback: direct gather (used only if ws too small) ----------------
__global__ __launch_bounds__(256) void k_naive(const float* __restrict__ input,
                                               const int* __restrict__ inds,
                                               const float* __restrict__ w,
                                               const float* __restrict__ bias,
                                               float* __restrict__ out) {
    const int tid = threadIdx.x;
    const int oq = tid & 7;
    const int rg = tid >> 3;
    const int row = blockIdx.x * 32 + rg;
    if (row >= N_ROWS) return;
    const int c = inds[row];
    const float4* xin = (const float4*)(input + (size_t)row * IN_F);
    const float4* wr = (const float4*)(w + (size_t)c * IN_F * OUT_F);
    float4 acc = ((const float4*)(bias + (size_t)c * OUT_F))[oq];
#pragma unroll
    for (int j = 0; j < 8; ++j) {
        const float4 xv = xin[j];
        const float a0 = xv.x, a1 = xv.y, a2 = xv.z, a3 = xv.w;
        const float4 w0 = wr[(j * 4 + 0) * (OUT_F / 4) + oq];
        const float4 w1 = wr[(j * 4 + 1) * (OUT_F / 4) + oq];
        const float4 w2 = wr[(j * 4 + 2) * (OUT_F / 4) + oq];
        const float4 w3 = wr[(j * 4 + 3) * (OUT_F / 4) + oq];
        acc.x += a0 * w0.x; acc.y += a0 * w0.y; acc.z += a0 * w0.z; acc.w += a0 * w0.w;
        acc.x += a1 * w1.x; acc.y += a1 * w1.y; acc.z += a1 * w1.z; acc.w += a1 * w1.w;
        acc.x += a2 * w2.x; acc.y += a2 * w2.y; acc.z += a2 * w2.z; acc.w += a2 * w2.w;
        acc.x += a3 * w3.x; acc.y += a3 * w3.y; acc.z += a3 * w3.z; acc.w += a3 * w3.w;
    }
    ((float4*)(out + (size_t)row * OUT_F))[oq] = acc;
}

extern "C" void kernel_launch(void* const* d_in, const int* in_sizes, int n_in,
                              void* d_out, int out_size, void* d_ws, size_t ws_size,
                              hipStream_t stream) {
    const float* input = (const float*)d_in[0];  // [N, 32] fp32
    const int*   inds  = (const int*)d_in[1];    // [N] int32
    const float* w     = (const float*)d_in[2];  // [1024, 32, 32] fp32
    const float* bias  = (const float*)d_in[3];  // [1024, 1, 32] fp32
    float* out = (float*)d_out;                  // [N, 32] fp32

    // ws layout (ints): bc[HB][1024] | cls_off[1025] (+3 pad) | rowids[N]
    int* ws = (int*)d_ws;
    int* bc      = ws;
    int* cls_off = ws + HB * N_CLASSES;
    int* rowids  = cls_off + N_CLASSES + 1 + 3;
    const size_t need = (size_t)(HB * N_CLASSES + N_CLASSES + 4 + N_ROWS) * sizeof(int);

    if (ws_size >= need) {
        k_hist<<<HB, 1024, 0, stream>>>(inds, bc);
        k_scan<<<1, 1024, 0, stream>>>(bc, cls_off);
        k_scatter<<<HB, 1024, 0, stream>>>(inds, bc, rowids);
        k_condmul<<<N_CLASSES, 256, 0, stream>>>(input, w, bias, rowids, cls_off, out);
    } else {
        k_naive<<<N_ROWS / 32, 256, 0, stream>>>(input, inds, w, bias, out);
    }
}

// Round 6
// 125.198 us; speedup vs baseline: 1.1873x; 1.1873x over previous
//
#include <hip/hip_runtime.h>

// CondMul: out[n] = input[n] @ w[inds[n]] + b[inds[n]]
// N=262144 rows, 1024 experts, in=out=32, fp32.
//
// v6 = v1 (proven-best kernel budget ~34us: hist 256t, LDS-cursor scatter,
// 1-stream LDS-w condmul) + ONE change: the scan is parallelized via a
// CLASS-MAJOR count matrix bcT[c][b] (contiguous per-thread int4 loads, no
// v[64] register array -- v5's reg-cached scan under launch_bounds(1024)
// capped VGPR at 64 and spilled to scratch on a single-block kernel, the
// likely ~20-30us regression).
//   K2a (1 block): per-class totals (16x int4 contiguous) + Hillis-Steele.
//   K2b (4 blocks): per-class prefix over the 64 hist-blocks, int4 in/out.
// Condmul untouched from v1: ~13us vs ~11us traffic floor.
// Fixed harness overhead: 2x ~43us 256MiB workspace-poison fills dominate
// dur_us; controllable kernel budget target ~26us.

#define N_ROWS      262144
#define N_CLASSES   1024
#define IN_F        32
#define OUT_F       32
#define HB          64
#define ROWS_PER_HB (N_ROWS / HB)   // 4096, exact

// ---------------- K1: per-block histogram (LDS atomics) ----------------
// Writes CLASS-MAJOR: bcT[c*HB + b] (1024 scattered 4B stores per block,
// fire-and-forget; makes K2a/K2b/scatter reads contiguous per class).
__global__ __launch_bounds__(256) void k_hist(const int* __restrict__ inds,
                                              int* __restrict__ bcT) {
    __shared__ int h[N_CLASSES];
    const int tid = threadIdx.x;
    for (int c = tid; c < N_CLASSES; c += 256) h[c] = 0;
    __syncthreads();
    const int base = blockIdx.x * ROWS_PER_HB;
    for (int k = 0; k < ROWS_PER_HB; k += 256)
        atomicAdd(&h[inds[base + k + tid]], 1);
    __syncthreads();
    for (int c = tid; c < N_CLASSES; c += 256)
        bcT[c * HB + blockIdx.x] = h[c];
}

// ------- K2a: single block; per-class totals + exclusive scan -> cls_off -------
// Thread c reads its own contiguous 64 counts (16x int4): wave pattern is 64
// lanes x distinct 64B lines = full-BW. No register arrays, no spill.
__global__ __launch_bounds__(1024) void k_scan(const int* __restrict__ bcT,
                                               int* __restrict__ cls_off) {
    __shared__ int s[N_CLASSES];
    const int c = threadIdx.x;  // 1024 threads == N_CLASSES
    const int4* p = (const int4*)(bcT + c * HB);
    int total = 0;
#pragma unroll
    for (int j = 0; j < HB / 4; ++j) {
        const int4 t = p[j];
        total += t.x + t.y + t.z + t.w;
    }
    s[c] = total;
    __syncthreads();
    // Hillis-Steele inclusive scan over classes
    for (int off = 1; off < N_CLASSES; off <<= 1) {
        int v = (c >= off) ? s[c - off] : 0;
        __syncthreads();
        s[c] += v;
        __syncthreads();
    }
    cls_off[c] = s[c] - total;  // exclusive prefix = class base
    if (c == N_CLASSES - 1) cls_off[N_CLASSES] = s[c];  // == N_ROWS
}

// ------- K2b: per-class prefix over hist-blocks (4 blocks x 256 threads) -------
// Thread-per-class: turn bcT[c][b] counts into global start offsets.
__global__ __launch_bounds__(256) void k_offsets(int* __restrict__ bcT,
                                                 const int* __restrict__ cls_off) {
    const int c = blockIdx.x * 256 + threadIdx.x;
    int run = cls_off[c];
    int4* p = (int4*)(bcT + c * HB);
#pragma unroll
    for (int j = 0; j < HB / 4; ++j) {
        const int4 t = p[j];
        int4 o;
        o.x = run; run += t.x;
        o.y = run; run += t.y;
        o.z = run; run += t.z;
        o.w = run; run += t.w;
        p[j] = o;
    }
}

// ---------------- K3: scatter row ids into buckets (LDS cursors) ----------------
// Deterministic ranges: block b's cursor for class c starts at bcT[c][b];
// all atomics are LDS-local.
__global__ __launch_bounds__(256) void k_scatter(const int* __restrict__ inds,
                                                 const int* __restrict__ bcT,
                                                 int* __restrict__ rowids) {
    __shared__ int cur[N_CLASSES];
    const int tid = threadIdx.x;
    for (int c = tid; c < N_CLASSES; c += 256)
        cur[c] = bcT[c * HB + blockIdx.x];
    __syncthreads();
    const int base = blockIdx.x * ROWS_PER_HB;
    for (int k = 0; k < ROWS_PER_HB; k += 256) {
        const int row = base + k + tid;
        const int c = inds[row];
        const int pos = atomicAdd(&cur[c], 1);
        rowids[pos] = row;
    }
}

// ---------------- K4: one block per expert, w in LDS (v1-proven) ----------------
// 256 threads = 4 waves. Lane -> (row-group rg = tid>>3, out-quad oq = tid&7).
// Each iteration: 32 rows; per lane a full input row in regs (8x float4),
// 32x ds_read_b128 of w (8 distinct addrs, broadcast -> conflict-free),
// 128 FMAs. ~64 VGPR -> high occupancy hides the random row gather.
__global__ __launch_bounds__(256) void k_condmul(const float* __restrict__ input,
                                                 const float* __restrict__ w,
                                                 const float* __restrict__ bias,
                                                 const int* __restrict__ rowids,
                                                 const int* __restrict__ cls_off,
                                                 float* __restrict__ out) {
    __shared__ float wlds[IN_F * OUT_F];  // 4 KiB
    const int cls = blockIdx.x;
    const int tid = threadIdx.x;

    // stage this expert's weights: 256 threads x 16 B = 4 KiB exactly
    ((float4*)wlds)[tid] = ((const float4*)(w + (size_t)cls * IN_F * OUT_F))[tid];

    const int oq = tid & 7;   // float4 column index (outputs oq*4 .. oq*4+3)
    const int rg = tid >> 3;  // 0..31 row slot within the block iteration
    const float4 bv = ((const float4*)(bias + (size_t)cls * OUT_F))[oq];
    const int start = cls_off[cls];
    const int count = cls_off[cls + 1] - start;
    __syncthreads();

    const float4* wl4 = (const float4*)wlds;
    const int iters = (count + 31) >> 5;
    for (int it = 0; it < iters; ++it) {
        const int ri = it * 32 + rg;
        const bool valid = ri < count;
        const int idx = valid ? ri : (count - 1);
        const int row = rowids[start + idx];

        const float4* xin = (const float4*)(input + (size_t)row * IN_F);
        float4 x[8];
#pragma unroll
        for (int j = 0; j < 8; ++j) x[j] = xin[j];

        float4 acc = bv;
#pragma unroll
        for (int j = 0; j < 8; ++j) {
            const float a0 = x[j].x, a1 = x[j].y, a2 = x[j].z, a3 = x[j].w;
            const float4 w0 = wl4[(j * 4 + 0) * (OUT_F / 4) + oq];
            const float4 w1 = wl4[(j * 4 + 1) * (OUT_F / 4) + oq];
            const float4 w2 = wl4[(j * 4 + 2) * (OUT_F / 4) + oq];
            const float4 w3 = wl4[(j * 4 + 3) * (OUT_F / 4) + oq];
            acc.x += a0 * w0.x; acc.y += a0 * w0.y; acc.z += a0 * w0.z; acc.w += a0 * w0.w;
            acc.x += a1 * w1.x; acc.y += a1 * w1.y; acc.z += a1 * w1.z; acc.w += a1 * w1.w;
            acc.x += a2 * w2.x; acc.y += a2 * w2.y; acc.z += a2 * w2.z; acc.w += a2 * w2.w;
            acc.x += a3 * w3.x; acc.y += a3 * w3.y; acc.z += a3 * w3.z; acc.w += a3 * w3.w;
        }
        if (valid)
            ((float4*)(out + (size_t)row * OUT_F))[oq] = acc;
    }
}

// ---------------- fallback: direct gather (used only if ws too small) ----------------
__global__ __launch_bounds__(256) void k_naive(const float* __restrict__ input,
                                               const int* __restrict__ inds,
                                               const float* __restrict__ w,
                                               const float* __restrict__ bias,
                                               float* __restrict__ out) {
    const int tid = threadIdx.x;
    const int oq = tid & 7;
    const int rg = tid >> 3;
    const int row = blockIdx.x * 32 + rg;
    if (row >= N_ROWS) return;
    const int c = inds[row];
    const float4* xin = (const float4*)(input + (size_t)row * IN_F);
    const float4* wr = (const float4*)(w + (size_t)c * IN_F * OUT_F);
    float4 acc = ((const float4*)(bias + (size_t)c * OUT_F))[oq];
#pragma unroll
    for (int j = 0; j < 8; ++j) {
        const float4 xv = xin[j];
        const float a0 = xv.x, a1 = xv.y, a2 = xv.z, a3 = xv.w;
        const float4 w0 = wr[(j * 4 + 0) * (OUT_F / 4) + oq];
        const float4 w1 = wr[(j * 4 + 1) * (OUT_F / 4) + oq];
        const float4 w2 = wr[(j * 4 + 2) * (OUT_F / 4) + oq];
        const float4 w3 = wr[(j * 4 + 3) * (OUT_F / 4) + oq];
        acc.x += a0 * w0.x; acc.y += a0 * w0.y; acc.z += a0 * w0.z; acc.w += a0 * w0.w;
        acc.x += a1 * w1.x; acc.y += a1 * w1.y; acc.z += a1 * w1.z; acc.w += a1 * w1.w;
        acc.x += a2 * w2.x; acc.y += a2 * w2.y; acc.z += a2 * w2.z; acc.w += a2 * w2.w;
        acc.x += a3 * w3.x; acc.y += a3 * w3.y; acc.z += a3 * w3.z; acc.w += a3 * w3.w;
    }
    ((float4*)(out + (size_t)row * OUT_F))[oq] = acc;
}

extern "C" void kernel_launch(void* const* d_in, const int* in_sizes, int n_in,
                              void* d_out, int out_size, void* d_ws, size_t ws_size,
                              hipStream_t stream) {
    const float* input = (const float*)d_in[0];  // [N, 32] fp32
    const int*   inds  = (const int*)d_in[1];    // [N] int32
    const float* w     = (const float*)d_in[2];  // [1024, 32, 32] fp32
    const float* bias  = (const float*)d_in[3];  // [1024, 1, 32] fp32
    float* out = (float*)d_out;                  // [N, 32] fp32

    // ws layout (ints): bcT[1024][HB] | cls_off[1025] (+3 pad) | rowids[N]
    int* ws = (int*)d_ws;
    int* bcT     = ws;                               // class-major counts/offsets
    int* cls_off = ws + N_CLASSES * HB;
    int* rowids  = cls_off + N_CLASSES + 1 + 3;
    const size_t need = (size_t)(N_CLASSES * HB + N_CLASSES + 4 + N_ROWS) * sizeof(int);

    if (ws_size >= need) {
        k_hist<<<HB, 256, 0, stream>>>(inds, bcT);
        k_scan<<<1, 1024, 0, stream>>>(bcT, cls_off);
        k_offsets<<<N_CLASSES / 256, 256, 0, stream>>>(bcT, cls_off);
        k_scatter<<<HB, 256, 0, stream>>>(inds, bcT, rowids);
        k_condmul<<<N_CLASSES, 256, 0, stream>>>(input, w, bias, rowids, cls_off, out);
    } else {
        k_naive<<<N_ROWS / 32, 256, 0, stream>>>(input, inds, w, bias, out);
    }
}